// Round 8
// baseline (180.641 us; speedup 1.0000x reference)
//
#include <hip/hip_runtime.h>
#include <hip/hip_bf16.h>
#include <math.h>

#define N_NODES 60000
#define IN_CH   128
#define HID     32
#define N_EDGES 600000
#define CAP     32

// workspace layout in 4-byte units
#define WS_CNT    0           // 60000 ints (+1 float sum right after)
#define WS_SUM    60000       // 1 float
#define WS_BUCKET 60008       // 60000*32 ints
#define WS_HS     2940032     // 60000*128 bf16 (dinv-SCALED h) -- 15.4 MB
#define WS_X      10620032    // 60000*64 uints (bf16x2 x)      -- 15.4 MB

typedef float  v4f __attribute__((ext_vector_type(4)));
typedef short  v8s __attribute__((ext_vector_type(8)));

static __device__ inline short f2bf(float f) {
    __hip_bfloat16 h = __float2bfloat16(f);   // RNE
    union { __hip_bfloat16 h; short s; } u; u.h = h; return u.s;
}
static __device__ inline float bf2f(short s) {
    return __uint_as_float(((unsigned int)(unsigned short)s) << 16);
}
static __device__ inline float bflo(unsigned int u) { return __uint_as_float(u << 16); }
static __device__ inline float bfhi(unsigned int u) { return __uint_as_float(u & 0xffff0000u); }
static __device__ inline int rdl_i(int v, int l) { return __builtin_amdgcn_readlane(v, l); }

// K1: hist. cnt[d] = in-degree(d); bucket[d*CAP+slot] = src. Max TLP (1 edge/thread).
__global__ void k_hist(const int* __restrict__ eidx, int* __restrict__ cnt,
                       int* __restrict__ bucket) {
    int i = blockIdx.x * blockDim.x + threadIdx.x;
    if (i >= N_EDGES) return;
    int s = eidx[i];
    int d = eidx[N_EDGES + i];
    int slot = atomicAdd(&cnt[d], 1);
    if (slot < CAP) bucket[d * CAP + slot] = s;
}

// K2: hs = bf16( dinv[row] * (state @ Wg) ). cnt is final (hist completed),
// so dinv folds into the epilogue for free -- gather then needs no per-src
// cnt loads or dv broadcasts.
__launch_bounds__(256)
__global__ void k_gemm(const float* __restrict__ state, const float* __restrict__ Wg,
                       const int* __restrict__ cnt, unsigned short* __restrict__ hs) {
    __shared__ __align__(16) short Bs[128 * 136];   // 34.8 KB
    const int t = threadIdx.x;

    // stage Wg -> Bs[n][k] (bf16, transposed)
    for (int idx = t; idx < 128 * 128; idx += 256) {
        int k = idx >> 7, n = idx & 127;
        Bs[n * 136 + k] = f2bf(Wg[idx]);
    }
    __syncthreads();

    const int w = t >> 6, lane = t & 63;
    const int quad = lane >> 4, m = lane & 15;
    const int rowBase = blockIdx.x * 64;
    int arow = rowBase + w * 16 + m;
    if (arow > N_NODES - 1) arow = N_NODES - 1;

    v8s a[4];
    const float4* sp = (const float4*)(state + (size_t)arow * 128);
#pragma unroll
    for (int q = 0; q < 4; ++q) {
        float4 v0 = sp[q * 8 + quad * 2];
        float4 v1 = sp[q * 8 + quad * 2 + 1];
        v8s af;
        af[0] = f2bf(v0.x); af[1] = f2bf(v0.y); af[2] = f2bf(v0.z); af[3] = f2bf(v0.w);
        af[4] = f2bf(v1.x); af[5] = f2bf(v1.y); af[6] = f2bf(v1.z); af[7] = f2bf(v1.w);
        a[q] = af;
    }

    v4f acc[8];
#pragma unroll
    for (int tt = 0; tt < 8; ++tt) acc[tt] = (v4f)0.f;

#pragma unroll
    for (int tt = 0; tt < 8; ++tt) {
        const short* bp = &Bs[(tt * 16 + m) * 136];
#pragma unroll
        for (int q = 0; q < 4; ++q) {
            v8s b = *(const v8s*)(bp + q * 32 + quad * 8);
            acc[tt] = __builtin_amdgcn_mfma_f32_16x16x32_bf16(a[q], b, acc[tt], 0, 0, 0);
        }
    }

    // epilogue: row = rowBase + w*16 + quad*4 + r, col = tt*16 + m; scale by dinv[row]
    float dinv[4];
#pragma unroll
    for (int r = 0; r < 4; ++r) {
        int rr = rowBase + w * 16 + quad * 4 + r;
        dinv[r] = (rr < N_NODES) ? rsqrtf((float)cnt[rr] + 1.0f) : 0.f;
    }
#pragma unroll
    for (int tt = 0; tt < 8; ++tt) {
#pragma unroll
        for (int r = 0; r < 4; ++r) {
            int rr = rowBase + w * 16 + quad * 4 + r;
            if (rr < N_NODES)
                hs[(size_t)rr * 128 + tt * 16 + m] = (unsigned short)f2bf(acc[tt][r] * dinv[r]);
        }
    }
}

// K3: gather (segment-sum of dinv-scaled bf16 hs rows) + bias/relu/residual
//     -> x (bf16x2). One wave per dst row (max TLP). Slot broadcast via
//     readlane only -- no per-src cnt loads, no dv math.
__launch_bounds__(256)
__global__ void k_gather(const unsigned short* __restrict__ hs, const float* __restrict__ state,
                         const int* __restrict__ cnt, const int* __restrict__ bucket,
                         const float* __restrict__ bg, unsigned int* __restrict__ xb) {
    const int wave = threadIdx.x >> 6, lane = threadIdx.x & 63;
    const int row = blockIdx.x * 4 + wave;
    if (row >= N_NODES) return;
    const int ci = cnt[row];
    const float dinv = rsqrtf((float)ci + 1.0f);
    const int nb = ci < CAP ? ci : CAP;

    int slot = (lane < nb) ? bucket[row * CAP + lane] : 0;

    const unsigned int* hp = (const unsigned int*)hs;   // bf16x2 per dword
    float ax, ay;
    {
        unsigned int u = hp[(unsigned)row * 64u + lane];   // self (already scaled)
        ax = bflo(u);
        ay = bfhi(u);
    }
    int s = 0;
    for (; s + 8 <= nb; s += 8) {
        int s0 = rdl_i(slot, s + 0), s1 = rdl_i(slot, s + 1);
        int s2 = rdl_i(slot, s + 2), s3 = rdl_i(slot, s + 3);
        int s4 = rdl_i(slot, s + 4), s5 = rdl_i(slot, s + 5);
        int s6 = rdl_i(slot, s + 6), s7 = rdl_i(slot, s + 7);
        unsigned int u0 = hp[(unsigned)s0 * 64u + lane];
        unsigned int u1 = hp[(unsigned)s1 * 64u + lane];
        unsigned int u2 = hp[(unsigned)s2 * 64u + lane];
        unsigned int u3 = hp[(unsigned)s3 * 64u + lane];
        unsigned int u4 = hp[(unsigned)s4 * 64u + lane];
        unsigned int u5 = hp[(unsigned)s5 * 64u + lane];
        unsigned int u6 = hp[(unsigned)s6 * 64u + lane];
        unsigned int u7 = hp[(unsigned)s7 * 64u + lane];
        ax += bflo(u0) + bflo(u1) + bflo(u2) + bflo(u3)
            + bflo(u4) + bflo(u5) + bflo(u6) + bflo(u7);
        ay += bfhi(u0) + bfhi(u1) + bfhi(u2) + bfhi(u3)
            + bfhi(u4) + bfhi(u5) + bfhi(u6) + bfhi(u7);
    }
    for (; s + 4 <= nb; s += 4) {
        int s0 = rdl_i(slot, s + 0), s1 = rdl_i(slot, s + 1);
        int s2 = rdl_i(slot, s + 2), s3 = rdl_i(slot, s + 3);
        unsigned int u0 = hp[(unsigned)s0 * 64u + lane];
        unsigned int u1 = hp[(unsigned)s1 * 64u + lane];
        unsigned int u2 = hp[(unsigned)s2 * 64u + lane];
        unsigned int u3 = hp[(unsigned)s3 * 64u + lane];
        ax += bflo(u0) + bflo(u1) + bflo(u2) + bflo(u3);
        ay += bfhi(u0) + bfhi(u1) + bfhi(u2) + bfhi(u3);
    }
    for (; s < nb; ++s) {
        int s0 = rdl_i(slot, s);
        unsigned int u = hp[(unsigned)s0 * 64u + lane];
        ax += bflo(u);
        ay += bfhi(u);
    }
    float2 bgv = ((const float2*)bg)[lane];
    float2 st  = ((const float2*)state)[(unsigned)row * 64u + lane];
    float ox = fmaxf(fmaf(dinv, ax, bgv.x), 0.f) + st.x;
    float oy = fmaxf(fmaf(dinv, ay, bgv.y), 0.f) + st.y;
    unsigned int pack = ((unsigned int)(unsigned short)f2bf(oy) << 16)
                      | ((unsigned int)(unsigned short)f2bf(ox));
    xb[(unsigned)row * 64u + lane] = pack;
}

// K4: MFMA MLP. Wave handles 16 rows.
// Layer1 (128->32): mfma_f32_16x16x32_bf16, W1 split hi+lo bf16 (fp32-accurate).
// Layer2/3 (32->32->1): fp32 scalar per-lane after wave-local LDS transpose.
__launch_bounds__(256)
__global__ void k_mlp(const unsigned int* __restrict__ xb,
                      const float* __restrict__ W1, const float* __restrict__ b1,
                      const float* __restrict__ W2, const float* __restrict__ b2,
                      const float* __restrict__ W3, const float* __restrict__ b3,
                      float* __restrict__ out, float* __restrict__ sum) {
    __shared__ __align__(16) short BsH[32 * 136];   // W1^T hi  (8.7 KB)
    __shared__ __align__(16) short BsL[32 * 136];   // W1^T lo  (8.7 KB)
    __shared__ float  zs[4][16 * 33];               // z1 per wave (8.4 KB)
    __shared__ float4 W2s[32 * 8];                  // 4 KB
    __shared__ float  b1s[32], b2s[32], W3s[32];
    __shared__ float  wred[4];
    const int t = threadIdx.x;

    // stage W1 (128x32 fp32 [k][j]) -> BsH/BsL [j][k] bf16 hi/lo
    for (int idx = t; idx < 128 * 32; idx += 256) {
        int k = idx >> 5, j = idx & 31;
        float f = W1[idx];
        short hi = f2bf(f);
        short lo = f2bf(f - bf2f(hi));
        BsH[j * 136 + k] = hi;
        BsL[j * 136 + k] = lo;
    }
    W2s[t] = ((const float4*)W2)[t];                // 32x32 fp32 = 256 float4
    if (t < 32) { b1s[t] = b1[t]; b2s[t] = b2[t]; W3s[t] = W3[t]; }
    __syncthreads();

    const int wv = t >> 6, lane = t & 63;
    const int quad = lane >> 4, m = lane & 15;
    const int rbase = (blockIdx.x * 4 + wv) * 16;   // 16 rows per wave
    float wavesum = 0.f;

    if (rbase < N_NODES) {   // 60000 % 16 == 0: active waves fully in-bounds
        v8s a[4];
        const int4* xp = (const int4*)(xb + (size_t)(rbase + m) * 64);
#pragma unroll
        for (int q = 0; q < 4; ++q) a[q] = *(const v8s*)&xp[q * 4 + quad];

        v4f acc0 = (v4f)0.f, acc1 = (v4f)0.f;
#pragma unroll
        for (int q = 0; q < 4; ++q) {
            v8s bh0 = *(const v8s*)&BsH[m * 136 + q * 32 + quad * 8];
            v8s bh1 = *(const v8s*)&BsH[(16 + m) * 136 + q * 32 + quad * 8];
            acc0 = __builtin_amdgcn_mfma_f32_16x16x32_bf16(a[q], bh0, acc0, 0, 0, 0);
            acc1 = __builtin_amdgcn_mfma_f32_16x16x32_bf16(a[q], bh1, acc1, 0, 0, 0);
        }
#pragma unroll
        for (int q = 0; q < 4; ++q) {
            v8s bl0 = *(const v8s*)&BsL[m * 136 + q * 32 + quad * 8];
            v8s bl1 = *(const v8s*)&BsL[(16 + m) * 136 + q * 32 + quad * 8];
            acc0 = __builtin_amdgcn_mfma_f32_16x16x32_bf16(a[q], bl0, acc0, 0, 0, 0);
            acc1 = __builtin_amdgcn_mfma_f32_16x16x32_bf16(a[q], bl1, acc1, 0, 0, 0);
        }

        // bias + leaky-relu, transpose into zs: C layout row=quad*4+r, col=m(+16)
        float bj0 = b1s[m], bj1 = b1s[16 + m];
#pragma unroll
        for (int r = 0; r < 4; ++r) {
            float h0 = acc0[r] + bj0; h0 = h0 > 0.f ? h0 : 0.01f * h0;
            float h1 = acc1[r] + bj1; h1 = h1 > 0.f ? h1 : 0.01f * h1;
            zs[wv][(quad * 4 + r) * 33 + m]      = h0;
            zs[wv][(quad * 4 + r) * 33 + 16 + m] = h1;
        }
        asm volatile("s_waitcnt lgkmcnt(0)" ::: "memory");   // wave-local RAW via LDS

        // layer2: lane handles row=m, channels j = quad*8..+8 (fp32)
        float h2[8];
#pragma unroll
        for (int j = 0; j < 8; ++j) h2[j] = b2s[quad * 8 + j];
        const float* zrow = &zs[wv][m * 33];
#pragma unroll
        for (int k = 0; k < 32; ++k) {
            float zk = zrow[k];
            float4 wA = W2s[k * 8 + quad * 2];
            float4 wB = W2s[k * 8 + quad * 2 + 1];
            h2[0] = fmaf(zk, wA.x, h2[0]); h2[1] = fmaf(zk, wA.y, h2[1]);
            h2[2] = fmaf(zk, wA.z, h2[2]); h2[3] = fmaf(zk, wA.w, h2[3]);
            h2[4] = fmaf(zk, wB.x, h2[4]); h2[5] = fmaf(zk, wB.y, h2[5]);
            h2[6] = fmaf(zk, wB.z, h2[6]); h2[7] = fmaf(zk, wB.w, h2[7]);
        }
        float a3p = 0.f;
#pragma unroll
        for (int j = 0; j < 8; ++j) {
            float z2 = h2[j] > 0.f ? h2[j] : 0.01f * h2[j];
            a3p = fmaf(z2, W3s[quad * 8 + j], a3p);
        }
        a3p += __shfl_xor(a3p, 16, 64);
        a3p += __shfl_xor(a3p, 32, 64);     // full dot in all quads
        float a3 = a3p + b3[0];
        float sp = fmaxf(a3, 0.f) + log1pf(expf(-fabsf(a3)));  // stable softplus
        if (quad == 0) out[rbase + m] = sp;
        float p = (quad == 0) ? sp : 0.f;   // count each row once
#pragma unroll
        for (int off = 32; off >= 1; off >>= 1) p += __shfl_xor(p, off, 64);
        wavesum = p;
    }
    if (lane == 0) wred[wv] = wavesum;
    __syncthreads();
    if (t == 0) atomicAdd(sum, (wred[0] + wred[1]) + (wred[2] + wred[3]));
}

// K5: in-place action = conc / (sum + 1e-20), float4-vectorized
__global__ void k_norm(const float* __restrict__ sum, float* __restrict__ out) {
    int i = blockIdx.x * blockDim.x + threadIdx.x;
    if (i < N_NODES / 4) {
        float inv = 1.0f / (*sum + 1e-20f);
        float4* o4 = (float4*)out;
        float4 v = o4[i];
        v.x *= inv; v.y *= inv; v.z *= inv; v.w *= inv;
        o4[i] = v;
    }
}

extern "C" void kernel_launch(void* const* d_in, const int* in_sizes, int n_in,
                              void* d_out, int out_size, void* d_ws, size_t ws_size,
                              hipStream_t stream) {
    const float* state = (const float*)d_in[0];
    const float* Wg    = (const float*)d_in[1];
    const float* bg    = (const float*)d_in[2];
    const float* W1    = (const float*)d_in[3];
    const float* b1    = (const float*)d_in[4];
    const float* W2    = (const float*)d_in[5];
    const float* b2    = (const float*)d_in[6];
    const float* W3    = (const float*)d_in[7];
    const float* b3    = (const float*)d_in[8];
    const int*   eidx  = (const int*)d_in[9];
    float* out = (float*)d_out;

    int*   wi = (int*)d_ws;
    float* wf = (float*)d_ws;
    int*   cnt    = wi + WS_CNT;
    float* sum    = wf + WS_SUM;
    int*   bucket = wi + WS_BUCKET;
    unsigned short* hs = (unsigned short*)(wf + WS_HS);
    unsigned int*   xb = (unsigned int*)(wf + WS_X);

    hipMemsetAsync(cnt, 0, 60001 * sizeof(int), stream);  // cnt + sum

    k_hist<<<(N_EDGES + 255) / 256, 256, 0, stream>>>(eidx, cnt, bucket);
    k_gemm<<<(N_NODES + 63) / 64, 256, 0, stream>>>(state, Wg, cnt, hs);
    k_gather<<<(N_NODES + 3) / 4, 256, 0, stream>>>(hs, state, cnt, bucket, bg, xb);
    k_mlp<<<938, 256, 0, stream>>>(xb, W1, b1, W2, b2, W3, b3, out, sum);
    k_norm<<<(N_NODES / 4 + 255) / 256, 256, 0, stream>>>(sum, out);
}

// Round 10
// 170.839 us; speedup vs baseline: 1.0574x; 1.0574x over previous
//
#include <hip/hip_runtime.h>
#include <hip/hip_bf16.h>
#include <math.h>

#define N_NODES 60000
#define IN_CH   128
#define HID     32
#define N_EDGES 600000
#define CAP     32

// workspace layout in 4-byte units
#define WS_CNT    0           // 60000 ints (+1 float sum right after)
#define WS_SUM    60000       // 1 float
#define WS_BUCKET 60008       // 60000*32 u16 (3.84 MB; one 64B line per dst row)
#define WS_HS     2940032     // 60000*128 bf16 (UNSCALED h) -- 15.4 MB
#define WS_X      10620032    // 60000*64 uints (bf16x2 x)   -- 15.4 MB

typedef float  v4f __attribute__((ext_vector_type(4)));
typedef short  v8s __attribute__((ext_vector_type(8)));

static __device__ inline short f2bf(float f) {
    __hip_bfloat16 h = __float2bfloat16(f);   // RNE
    union { __hip_bfloat16 h; short s; } u; u.h = h; return u.s;
}
static __device__ inline float bf2f(short s) {
    return __uint_as_float(((unsigned int)(unsigned short)s) << 16);
}
static __device__ inline float bflo(unsigned int u) { return __uint_as_float(u << 16); }
static __device__ inline float bfhi(unsigned int u) { return __uint_as_float(u & 0xffff0000u); }
static __device__ inline int   rdl_i(int v, int l)   { return __builtin_amdgcn_readlane(v, l); }
static __device__ inline float rdl_f(float v, int l) {
    return __int_as_float(__builtin_amdgcn_readlane(__float_as_int(v), l));
}

// K1 (fat): hist role + gemm role in one launch (R4 proven structure).
// hist:  cnt[d] = in-degree(d); bucket16[d*CAP+slot] = (u16)src  -- src<60000<65536.
//        u16 bucket => one 64B line per dst row: kills cross-XCD line bouncing.
// gemm:  hs = bf16(state @ Wg)  -- UNSCALED (dinv applied in gather)
// Role split 2:5 by blockIdx%7 so both roles interleave across CUs.
__launch_bounds__(256)
__global__ void k_fat(const float* __restrict__ state, const float* __restrict__ Wg,
                      const int* __restrict__ eidx, int* __restrict__ cnt,
                      unsigned short* __restrict__ bucket, unsigned short* __restrict__ hs) {
    __shared__ __align__(16) short Bs[128 * 136];   // 34.8 KB (gemm role only)
    const int bid = blockIdx.x;
    const int r7 = bid % 7, q7 = bid / 7;
    const int t = threadIdx.x;

    if (r7 >= 2) {
        // ---- hist role: 2344 blocks x 256 edges, 1 edge/thread (max TLP) ----
        const int hb = q7 * 5 + (r7 - 2);
        const int i = hb * 256 + t;
        if (i < N_EDGES) {
            int s = eidx[i];
            int d = eidx[N_EDGES + i];
            int slot = atomicAdd(&cnt[d], 1);
            if (slot < CAP) bucket[d * CAP + slot] = (unsigned short)s;
        }
        return;
    }

    // ---- gemm role: 938 blocks x 64 rows ----
    const int gb = q7 * 2 + r7;

    // stage Wg -> Bs[n][k] (bf16, transposed)
    for (int idx = t; idx < 128 * 128; idx += 256) {
        int k = idx >> 7, n = idx & 127;
        Bs[n * 136 + k] = f2bf(Wg[idx]);
    }
    __syncthreads();

    const int w = t >> 6, lane = t & 63;
    const int quad = lane >> 4, m = lane & 15;
    const int rowBase = gb * 64;
    int arow = rowBase + w * 16 + m;
    if (arow > N_NODES - 1) arow = N_NODES - 1;

    v8s a[4];
    const float4* sp = (const float4*)(state + (size_t)arow * 128);
#pragma unroll
    for (int q = 0; q < 4; ++q) {
        float4 v0 = sp[q * 8 + quad * 2];
        float4 v1 = sp[q * 8 + quad * 2 + 1];
        v8s af;
        af[0] = f2bf(v0.x); af[1] = f2bf(v0.y); af[2] = f2bf(v0.z); af[3] = f2bf(v0.w);
        af[4] = f2bf(v1.x); af[5] = f2bf(v1.y); af[6] = f2bf(v1.z); af[7] = f2bf(v1.w);
        a[q] = af;
    }

    v4f acc[8];
#pragma unroll
    for (int tt = 0; tt < 8; ++tt) acc[tt] = (v4f)0.f;

#pragma unroll
    for (int tt = 0; tt < 8; ++tt) {
        const short* bp = &Bs[(tt * 16 + m) * 136];
#pragma unroll
        for (int q = 0; q < 4; ++q) {
            v8s b = *(const v8s*)(bp + q * 32 + quad * 8);
            acc[tt] = __builtin_amdgcn_mfma_f32_16x16x32_bf16(a[q], b, acc[tt], 0, 0, 0);
        }
    }

    // epilogue: row = rowBase + w*16 + quad*4 + r, col = tt*16 + m  (no dinv)
#pragma unroll
    for (int tt = 0; tt < 8; ++tt) {
#pragma unroll
        for (int r = 0; r < 4; ++r) {
            int rr = rowBase + w * 16 + quad * 4 + r;
            if (rr < N_NODES)
                hs[(size_t)rr * 128 + tt * 16 + m] = (unsigned short)f2bf(acc[tt][r]);
        }
    }
}

// K2: gather (segment-sum of bf16 h rows, per-src dinv applied here)
//     + bias/relu/residual -> x (bf16x2). One wave per dst row (max TLP).
//     Broadcasts via readlane; bucket reads are u16 (one line per row).
__launch_bounds__(256)
__global__ void k_gather(const unsigned short* __restrict__ hs, const float* __restrict__ state,
                         const int* __restrict__ cnt, const unsigned short* __restrict__ bucket,
                         const float* __restrict__ bg, unsigned int* __restrict__ xb) {
    const int wave = threadIdx.x >> 6, lane = threadIdx.x & 63;
    const int row = blockIdx.x * 4 + wave;
    if (row >= N_NODES) return;
    const int ci = cnt[row];
    const float dinv = rsqrtf((float)ci + 1.0f);
    const int nb = ci < CAP ? ci : CAP;

    int slot = 0; float dv = 0.f;
    if (lane < nb) {
        slot = (int)bucket[row * CAP + lane];
        dv = rsqrtf((float)cnt[slot] + 1.0f);
    }

    const unsigned int* hp = (const unsigned int*)hs;   // bf16x2 per dword
    float ax, ay;
    {
        unsigned int u = hp[(unsigned)row * 64u + lane];   // self term
        ax = bflo(u) * dinv;
        ay = bfhi(u) * dinv;
    }
    int s = 0;
    for (; s + 8 <= nb; s += 8) {
        int   s0 = rdl_i(slot, s + 0), s1 = rdl_i(slot, s + 1);
        int   s2 = rdl_i(slot, s + 2), s3 = rdl_i(slot, s + 3);
        int   s4 = rdl_i(slot, s + 4), s5 = rdl_i(slot, s + 5);
        int   s6 = rdl_i(slot, s + 6), s7 = rdl_i(slot, s + 7);
        float d0 = rdl_f(dv, s + 0), d1 = rdl_f(dv, s + 1);
        float d2 = rdl_f(dv, s + 2), d3 = rdl_f(dv, s + 3);
        float d4 = rdl_f(dv, s + 4), d5 = rdl_f(dv, s + 5);
        float d6 = rdl_f(dv, s + 6), d7 = rdl_f(dv, s + 7);
        unsigned int u0 = hp[(unsigned)s0 * 64u + lane];
        unsigned int u1 = hp[(unsigned)s1 * 64u + lane];
        unsigned int u2 = hp[(unsigned)s2 * 64u + lane];
        unsigned int u3 = hp[(unsigned)s3 * 64u + lane];
        unsigned int u4 = hp[(unsigned)s4 * 64u + lane];
        unsigned int u5 = hp[(unsigned)s5 * 64u + lane];
        unsigned int u6 = hp[(unsigned)s6 * 64u + lane];
        unsigned int u7 = hp[(unsigned)s7 * 64u + lane];
        ax = fmaf(d0, bflo(u0), ax); ay = fmaf(d0, bfhi(u0), ay);
        ax = fmaf(d1, bflo(u1), ax); ay = fmaf(d1, bfhi(u1), ay);
        ax = fmaf(d2, bflo(u2), ax); ay = fmaf(d2, bfhi(u2), ay);
        ax = fmaf(d3, bflo(u3), ax); ay = fmaf(d3, bfhi(u3), ay);
        ax = fmaf(d4, bflo(u4), ax); ay = fmaf(d4, bfhi(u4), ay);
        ax = fmaf(d5, bflo(u5), ax); ay = fmaf(d5, bfhi(u5), ay);
        ax = fmaf(d6, bflo(u6), ax); ay = fmaf(d6, bfhi(u6), ay);
        ax = fmaf(d7, bflo(u7), ax); ay = fmaf(d7, bfhi(u7), ay);
    }
    for (; s + 4 <= nb; s += 4) {
        int   s0 = rdl_i(slot, s + 0), s1 = rdl_i(slot, s + 1);
        int   s2 = rdl_i(slot, s + 2), s3 = rdl_i(slot, s + 3);
        float d0 = rdl_f(dv, s + 0), d1 = rdl_f(dv, s + 1);
        float d2 = rdl_f(dv, s + 2), d3 = rdl_f(dv, s + 3);
        unsigned int u0 = hp[(unsigned)s0 * 64u + lane];
        unsigned int u1 = hp[(unsigned)s1 * 64u + lane];
        unsigned int u2 = hp[(unsigned)s2 * 64u + lane];
        unsigned int u3 = hp[(unsigned)s3 * 64u + lane];
        ax = fmaf(d0, bflo(u0), ax); ay = fmaf(d0, bfhi(u0), ay);
        ax = fmaf(d1, bflo(u1), ax); ay = fmaf(d1, bfhi(u1), ay);
        ax = fmaf(d2, bflo(u2), ax); ay = fmaf(d2, bfhi(u2), ay);
        ax = fmaf(d3, bflo(u3), ax); ay = fmaf(d3, bfhi(u3), ay);
    }
    for (; s < nb; ++s) {
        int   s0 = rdl_i(slot, s);
        float d0 = rdl_f(dv, s);
        unsigned int u = hp[(unsigned)s0 * 64u + lane];
        ax = fmaf(d0, bflo(u), ax);
        ay = fmaf(d0, bfhi(u), ay);
    }
    float2 bgv = ((const float2*)bg)[lane];
    float2 st  = ((const float2*)state)[(unsigned)row * 64u + lane];
    float ox = fmaxf(fmaf(dinv, ax, bgv.x), 0.f) + st.x;
    float oy = fmaxf(fmaf(dinv, ay, bgv.y), 0.f) + st.y;
    unsigned int pack = ((unsigned int)(unsigned short)f2bf(oy) << 16)
                      | ((unsigned int)(unsigned short)f2bf(ox));
    xb[(unsigned)row * 64u + lane] = pack;
}

// K3: MFMA MLP. Wave handles 16 rows.
// Layer1 (128->32): mfma_f32_16x16x32_bf16, W1 split hi+lo bf16 (fp32-accurate).
// Layer2/3 (32->32->1): fp32 scalar per-lane after wave-local LDS transpose.
__launch_bounds__(256)
__global__ void k_mlp(const unsigned int* __restrict__ xb,
                      const float* __restrict__ W1, const float* __restrict__ b1,
                      const float* __restrict__ W2, const float* __restrict__ b2,
                      const float* __restrict__ W3, const float* __restrict__ b3,
                      float* __restrict__ out, float* __restrict__ sum) {
    __shared__ __align__(16) short BsH[32 * 136];   // W1^T hi  (8.7 KB)
    __shared__ __align__(16) short BsL[32 * 136];   // W1^T lo  (8.7 KB)
    __shared__ float  zs[4][16 * 33];               // z1 per wave (8.4 KB)
    __shared__ float4 W2s[32 * 8];                  // 4 KB
    __shared__ float  b1s[32], b2s[32], W3s[32];
    __shared__ float  wred[4];
    const int t = threadIdx.x;

    // stage W1 (128x32 fp32 [k][j]) -> BsH/BsL [j][k] bf16 hi/lo
    for (int idx = t; idx < 128 * 32; idx += 256) {
        int k = idx >> 5, j = idx & 31;
        float f = W1[idx];
        short hi = f2bf(f);
        short lo = f2bf(f - bf2f(hi));
        BsH[j * 136 + k] = hi;
        BsL[j * 136 + k] = lo;
    }
    W2s[t] = ((const float4*)W2)[t];                // 32x32 fp32 = 256 float4
    if (t < 32) { b1s[t] = b1[t]; b2s[t] = b2[t]; W3s[t] = W3[t]; }
    __syncthreads();

    const int wv = t >> 6, lane = t & 63;
    const int quad = lane >> 4, m = lane & 15;
    const int rbase = (blockIdx.x * 4 + wv) * 16;   // 16 rows per wave
    float wavesum = 0.f;

    if (rbase < N_NODES) {   // 60000 % 16 == 0: active waves fully in-bounds
        v8s a[4];
        const int4* xp = (const int4*)(xb + (size_t)(rbase + m) * 64);
#pragma unroll
        for (int q = 0; q < 4; ++q) a[q] = *(const v8s*)&xp[q * 4 + quad];

        v4f acc0 = (v4f)0.f, acc1 = (v4f)0.f;
#pragma unroll
        for (int q = 0; q < 4; ++q) {
            v8s bh0 = *(const v8s*)&BsH[m * 136 + q * 32 + quad * 8];
            v8s bh1 = *(const v8s*)&BsH[(16 + m) * 136 + q * 32 + quad * 8];
            acc0 = __builtin_amdgcn_mfma_f32_16x16x32_bf16(a[q], bh0, acc0, 0, 0, 0);
            acc1 = __builtin_amdgcn_mfma_f32_16x16x32_bf16(a[q], bh1, acc1, 0, 0, 0);
        }
#pragma unroll
        for (int q = 0; q < 4; ++q) {
            v8s bl0 = *(const v8s*)&BsL[m * 136 + q * 32 + quad * 8];
            v8s bl1 = *(const v8s*)&BsL[(16 + m) * 136 + q * 32 + quad * 8];
            acc0 = __builtin_amdgcn_mfma_f32_16x16x32_bf16(a[q], bl0, acc0, 0, 0, 0);
            acc1 = __builtin_amdgcn_mfma_f32_16x16x32_bf16(a[q], bl1, acc1, 0, 0, 0);
        }

        // bias + leaky-relu, transpose into zs: C layout row=quad*4+r, col=m(+16)
        float bj0 = b1s[m], bj1 = b1s[16 + m];
#pragma unroll
        for (int r = 0; r < 4; ++r) {
            float h0 = acc0[r] + bj0; h0 = h0 > 0.f ? h0 : 0.01f * h0;
            float h1 = acc1[r] + bj1; h1 = h1 > 0.f ? h1 : 0.01f * h1;
            zs[wv][(quad * 4 + r) * 33 + m]      = h0;
            zs[wv][(quad * 4 + r) * 33 + 16 + m] = h1;
        }
        asm volatile("s_waitcnt lgkmcnt(0)" ::: "memory");   // wave-local RAW via LDS

        // layer2: lane handles row=m, channels j = quad*8..+8 (fp32)
        float h2[8];
#pragma unroll
        for (int j = 0; j < 8; ++j) h2[j] = b2s[quad * 8 + j];
        const float* zrow = &zs[wv][m * 33];
#pragma unroll
        for (int k = 0; k < 32; ++k) {
            float zk = zrow[k];
            float4 wA = W2s[k * 8 + quad * 2];
            float4 wB = W2s[k * 8 + quad * 2 + 1];
            h2[0] = fmaf(zk, wA.x, h2[0]); h2[1] = fmaf(zk, wA.y, h2[1]);
            h2[2] = fmaf(zk, wA.z, h2[2]); h2[3] = fmaf(zk, wA.w, h2[3]);
            h2[4] = fmaf(zk, wB.x, h2[4]); h2[5] = fmaf(zk, wB.y, h2[5]);
            h2[6] = fmaf(zk, wB.z, h2[6]); h2[7] = fmaf(zk, wB.w, h2[7]);
        }
        float a3p = 0.f;
#pragma unroll
        for (int j = 0; j < 8; ++j) {
            float z2 = h2[j] > 0.f ? h2[j] : 0.01f * h2[j];
            a3p = fmaf(z2, W3s[quad * 8 + j], a3p);
        }
        a3p += __shfl_xor(a3p, 16, 64);
        a3p += __shfl_xor(a3p, 32, 64);     // full dot in all quads
        float a3 = a3p + b3[0];
        float sp = fmaxf(a3, 0.f) + log1pf(expf(-fabsf(a3)));  // stable softplus
        if (quad == 0) out[rbase + m] = sp;
        float p = (quad == 0) ? sp : 0.f;   // count each row once
#pragma unroll
        for (int off = 32; off >= 1; off >>= 1) p += __shfl_xor(p, off, 64);
        wavesum = p;
    }
    if (lane == 0) wred[wv] = wavesum;
    __syncthreads();
    if (t == 0) atomicAdd(sum, (wred[0] + wred[1]) + (wred[2] + wred[3]));
}

// K4: in-place action = conc / (sum + 1e-20), float4-vectorized
__global__ void k_norm(const float* __restrict__ sum, float* __restrict__ out) {
    int i = blockIdx.x * blockDim.x + threadIdx.x;
    if (i < N_NODES / 4) {
        float inv = 1.0f / (*sum + 1e-20f);
        float4* o4 = (float4*)out;
        float4 v = o4[i];
        v.x *= inv; v.y *= inv; v.z *= inv; v.w *= inv;
        o4[i] = v;
    }
}

extern "C" void kernel_launch(void* const* d_in, const int* in_sizes, int n_in,
                              void* d_out, int out_size, void* d_ws, size_t ws_size,
                              hipStream_t stream) {
    const float* state = (const float*)d_in[0];
    const float* Wg    = (const float*)d_in[1];
    const float* bg    = (const float*)d_in[2];
    const float* W1    = (const float*)d_in[3];
    const float* b1    = (const float*)d_in[4];
    const float* W2    = (const float*)d_in[5];
    const float* b2    = (const float*)d_in[6];
    const float* W3    = (const float*)d_in[7];
    const float* b3    = (const float*)d_in[8];
    const int*   eidx  = (const int*)d_in[9];
    float* out = (float*)d_out;

    int*   wi = (int*)d_ws;
    float* wf = (float*)d_ws;
    int*   cnt    = wi + WS_CNT;
    float* sum    = wf + WS_SUM;
    unsigned short* bucket = (unsigned short*)(wi + WS_BUCKET);
    unsigned short* hs = (unsigned short*)(wf + WS_HS);
    unsigned int*   xb = (unsigned int*)(wf + WS_X);

    hipMemsetAsync(cnt, 0, 60001 * sizeof(int), stream);  // cnt + sum

    // fat: 938 gemm blocks (r7<2) + 2344 hist blocks (r7>=2) = 3282
    k_fat<<<3282, 256, 0, stream>>>(state, Wg, eidx, cnt, bucket, hs);
    k_gather<<<(N_NODES + 3) / 4, 256, 0, stream>>>(hs, state, cnt, bucket, bg, xb);
    // mlp: 16 rows/wave, 4 waves/block -> 938 blocks
    k_mlp<<<938, 256, 0, stream>>>(xb, W1, b1, W2, b2, W3, b3, out, sum);
    k_norm<<<(N_NODES / 4 + 255) / 256, 256, 0, stream>>>(sum, out);
}